// Round 9
// baseline (675.411 us; speedup 1.0000x reference)
//
#include <hip/hip_runtime.h>
#include <cstdint>
#include <cstddef>

// Qwen2 MoE MLP block. T=1024 H=2048 I=1408 SI=5632 E=8 K=4, scale=0.5.
// fp32 interface (runtime-detected, bf16 fallback). Internal: f16, fp32 accum.
//
// FULL path (ws >= ~340MB), 6 launches:
//   detect -> router_conv ->
//   prep_gu  : tcvt(Wsg,Wsu,Wg,Wu) 16896 blocks + compact as block 16896
//   gu_fused : gu GEMM BM=256 / 8-wave (512 thr; halves B-panel re-reads ->
//              lower L2/L3 byte demand) INTERLEAVED 1:4 with tcvt(Wd,Wsd)
//              (2 tiles per 512-thr block)
//   down_gemm_t: R0-proven body; per-expert K=1408 compacted + 2 shared chunks
//   final_g  : out[t] = 0.5*(sh0+sh1 + sum of token's 4 compacted rows)
// FALLBACK path (small ws): round-3 register-staging kernels (dense).

typedef unsigned short u16;
typedef _Float16 f16;
typedef __attribute__((ext_vector_type(8))) _Float16 half8;
typedef __attribute__((ext_vector_type(4))) float f32x4;

#define GLDS(g, l) __builtin_amdgcn_global_load_lds(                          \
    (const __attribute__((address_space(1))) void*)(g),                       \
    (__attribute__((address_space(3))) void*)(l), 16, 0, 0)

__device__ __forceinline__ float b2f(u16 u){ return __uint_as_float(((uint32_t)u)<<16); }
__device__ __forceinline__ u16 f2b(float f){
  uint32_t x = __float_as_uint(f);
  return (u16)((x + 0x7fffu + ((x>>16)&1u)) >> 16);   // RNE
}

// ---------------- dtype detection ----------------
__global__ __launch_bounds__(64) void detect_kernel(const uint32_t* __restrict__ X,
                                                    int* __restrict__ flag){
  const int lane = threadIdx.x;
  int cnt = 0;
  for (int i = lane; i < 256; i += 64){
    const uint32_t e = (X[i] >> 23) & 0xffu;
    cnt += (e >= 90u && e <= 160u) ? 1 : 0;
  }
#pragma unroll
  for (int off = 32; off > 0; off >>= 1) cnt += __shfl_xor(cnt, off, 64);
  if (lane == 0) *flag = (cnt > 128) ? 1 : 0;
}

// ---------------- fused router + X->f16 convert ----------------
template<bool F32>
__device__ void router_conv_body(const void* X, const void* Wr, const void* Wxg,
                                 f16* __restrict__ Xh, float* __restrict__ combine,
                                 float* __restrict__ sgate, float (*red)[9]){
  const int t = blockIdx.x, tid = threadIdx.x, lane = tid&63, wave = tid>>6;
  const int h0 = tid*8;
  float xv[8], gv[8];
  if (F32){
    const float* xp = (const float*)X + (size_t)t*2048 + h0;
    const float4 a = *(const float4*)xp, b = *(const float4*)(xp+4);
    xv[0]=a.x; xv[1]=a.y; xv[2]=a.z; xv[3]=a.w;
    xv[4]=b.x; xv[5]=b.y; xv[6]=b.z; xv[7]=b.w;
    const float* gp = (const float*)Wxg + h0;
    const float4 c = *(const float4*)gp, d = *(const float4*)(gp+4);
    gv[0]=c.x; gv[1]=c.y; gv[2]=c.z; gv[3]=c.w;
    gv[4]=d.x; gv[5]=d.y; gv[6]=d.z; gv[7]=d.w;
  } else {
    union { uint4 v; u16 s[8]; } xr, gr;
    xr.v = *(const uint4*)((const u16*)X + (size_t)t*2048 + h0);
    gr.v = *(const uint4*)((const u16*)Wxg + h0);
#pragma unroll
    for (int q = 0; q < 8; ++q){ xv[q] = b2f(xr.s[q]); gv[q] = b2f(gr.s[q]); }
  }
  half8 h8;
#pragma unroll
  for (int j = 0; j < 8; ++j) h8[j] = (f16)xv[j];
  *(half8*)(Xh + (size_t)t*2048 + h0) = h8;

  float acc[8] = {0,0,0,0,0,0,0,0};
  float ag = 0.f;
#pragma unroll
  for (int jj = 0; jj < 8; ++jj){
    const int h = h0 + jj;
    float w[8];
    if (F32){
      const float* wp = (const float*)Wr + (size_t)h*8;
      const float4 w0 = *(const float4*)wp, w1 = *(const float4*)(wp+4);
      w[0]=w0.x; w[1]=w0.y; w[2]=w0.z; w[3]=w0.w;
      w[4]=w1.x; w[5]=w1.y; w[6]=w1.z; w[7]=w1.w;
    } else {
      union { uint4 v; u16 s[8]; } wv;
      wv.v = *(const uint4*)((const u16*)Wr + (size_t)h*8);
#pragma unroll
      for (int q = 0; q < 8; ++q) w[q] = b2f(wv.s[q]);
    }
#pragma unroll
    for (int e = 0; e < 8; ++e) acc[e] += xv[jj] * w[e];
    ag += xv[jj] * gv[jj];
  }
#pragma unroll
  for (int off = 32; off > 0; off >>= 1){
#pragma unroll
    for (int e = 0; e < 8; ++e) acc[e] += __shfl_xor(acc[e], off, 64);
    ag += __shfl_xor(ag, off, 64);
  }
  if (lane == 0){
#pragma unroll
    for (int e = 0; e < 8; ++e) red[wave][e] = acc[e];
    red[wave][8] = ag;
  }
  __syncthreads();
  if (tid == 0){
    float a[8], g = 0.f;
#pragma unroll
    for (int e = 0; e < 8; ++e) a[e] = red[0][e] + red[1][e] + red[2][e] + red[3][e];
    g = red[0][8] + red[1][8] + red[2][8] + red[3][8];
    float m = a[0];
#pragma unroll
    for (int e = 1; e < 8; ++e) m = fmaxf(m, a[e]);
    float p[8]; float s = 0.f;
#pragma unroll
    for (int e = 0; e < 8; ++e){ p[e] = __expf(a[e]-m); s += p[e]; }
    const float inv = 1.f/s;
#pragma unroll
    for (int e = 0; e < 8; ++e) p[e] *= inv;
#pragma unroll
    for (int e = 0; e < 8; ++e){
      int cnt = 0;
#pragma unroll
      for (int j = 0; j < 8; ++j)
        cnt += (p[j] > p[e]) || (p[j] == p[e] && j < e);
      combine[(size_t)t*8 + e] = (cnt < 4) ? p[e] : 0.f;
    }
    sgate[t] = 1.f/(1.f + __expf(-g));
  }
}
__global__ __launch_bounds__(256) void router_conv(const void* X, const void* Wr, const void* Wxg,
                                                   f16* Xh, float* combine, float* sgate,
                                                   const int* flag){
  __shared__ float red[4][9];
  if (*flag) router_conv_body<true >(X, Wr, Wxg, Xh, combine, sgate, red);
  else       router_conv_body<false>(X, Wr, Wxg, Xh, combine, sgate, red);
}

// ---------------- routed-token compaction (256-thread device body) ----------------
__device__ void compact256(const float* __restrict__ combine, int* __restrict__ cnt,
                           int* __restrict__ tok, float* __restrict__ cw,
                           int* __restrict__ inv, int* lc){
  const int tid = threadIdx.x;
  if (tid < 8) lc[tid] = 0;
  __syncthreads();
#pragma unroll
  for (int s = 0; s < 4; ++s){
    const int t = s*256 + tid;
    int k = 0;
#pragma unroll
    for (int e = 0; e < 8; ++e){
      const float v = combine[(size_t)t*8 + e];
      if (v > 0.f){
        const int p = atomicAdd(&lc[e], 1);
        tok[e*1024 + p] = t;
        cw [e*1024 + p] = v;
        if (k < 4) inv[t*4 + k] = e*1024 + p;
        ++k;
      }
    }
    for (; k < 4; ++k) inv[t*4 + k] = -1;
  }
  __syncthreads();
#pragma unroll
  for (int e = 0; e < 8; ++e)
    for (int i = tid; i < 1024; i += 256)
      if (i >= lc[e]){ tok[e*1024 + i] = 0; cw[e*1024 + i] = 0.f; }
  if (tid < 8) cnt[tid] = lc[tid];
}

// ---------------- weight transpose+convert (64k x 64n tile; local-tid variant) ----------------
#define TP 72   // LDS tile row stride (f16): 144B -> 16B-aligned half8 reads
template<bool F32>
__device__ void tcvt64(const void* S, f16* __restrict__ Dm, int K, int N,
                       size_t soff, int n0, int k0, f16* Tt, int t){
  const int kr = t >> 4, nc = (t & 15)*4;
#pragma unroll
  for (int p = 0; p < 4; ++p){
    const int kk = p*16 + kr;
    float v0, v1, v2, v3;
    if (F32){
      const float* Sm = (const float*)S + soff;
      const float4 v = *(const float4*)(Sm + (size_t)(k0+kk)*N + n0 + nc);
      v0=v.x; v1=v.y; v2=v.z; v3=v.w;
    } else {
      const u16* Sm = (const u16*)S + soff;
      union { uint2 u; u16 s[4]; } r;
      r.u = *(const uint2*)(Sm + (size_t)(k0+kk)*N + n0 + nc);
      v0=b2f(r.s[0]); v1=b2f(r.s[1]); v2=b2f(r.s[2]); v3=b2f(r.s[3]);
    }
    Tt[(nc+0)*TP + kk] = (f16)v0;
    Tt[(nc+1)*TP + kk] = (f16)v1;
    Tt[(nc+2)*TP + kk] = (f16)v2;
    Tt[(nc+3)*TP + kk] = (f16)v3;
  }
  __syncthreads();
  const int nr = t >> 3, kc = (t & 7)*8;
#pragma unroll
  for (int p = 0; p < 2; ++p){
    const int n = p*32 + nr;
    const half8 v = *(const half8*)(Tt + n*TP + kc);
    *(half8*)(Dm + (size_t)(n0+n)*K + k0 + kc) = v;
  }
}

// ---------------- prep_gu: tcvt(Wsg,Wsu,Wg,Wu) + compact as last block ----------------
// segments (64x64 tiles): Wsg 2816 | Wsu 2816 | Wg 8*704 | Wu 8*704 => 16896,
// block 16896 = compact (overlaps with the transpose stream).
__global__ __launch_bounds__(256) void prep_gu(
    const void* Wsg, const void* Wsu, const void* Wg, const void* Wu,
    f16* WsgT, f16* WsuT, f16* WgT, f16* WuT,
    const float* combine, int* cnt, int* tok, float* cw, int* inv,
    const int* flag){
  __shared__ f16 Tt[64*TP];
  int bid = blockIdx.x;
  if (bid == 16896){
    compact256(combine, cnt, tok, cw, inv, (int*)Tt);
    return;
  }
  const void* S; f16* D; int K, N, nx; size_t soff = 0;
  if (bid < 2816){ S = Wsg; D = WsgT; K = 2048; N = 5632; nx = 88; }
  else if (bid < 5632){ bid -= 2816; S = Wsu; D = WsuT; K = 2048; N = 5632; nx = 88; }
  else if (bid < 11264){
    bid -= 5632; const int z = bid/704; bid -= z*704;
    soff = (size_t)z*2048*1408;
    S = Wg; D = WgT + soff; K = 2048; N = 1408; nx = 22;
  } else {
    bid -= 11264; const int z = bid/704; bid -= z*704;
    soff = (size_t)z*2048*1408;
    S = Wu; D = WuT + soff; K = 2048; N = 1408; nx = 22;
  }
  const int n0 = (bid % nx)*64, k0 = (bid / nx)*64;
  if (*flag) tcvt64<true >(S, D, K, N, soff, n0, k0, Tt, threadIdx.x);
  else       tcvt64<false>(S, D, K, N, soff, n0, k0, Tt, threadIdx.x);
}

// ---------------- async staging (f16, k-contiguous rows; 4-wave kernels) ----------------
__device__ __forceinline__ void stage_T128(const f16* __restrict__ Row, int ld, int k0, f16* Ls){
  const int tid = threadIdx.x, wave = tid>>6, lane = tid&63;
#pragma unroll
  for (int i = 0; i < 2; ++i){
    const int rbase = i*64 + wave*16;
    const f16* g = Row + (size_t)(rbase + (lane>>2))*ld + (k0 + (lane&3)*8);
    GLDS(g, Ls + rbase*32);
  }
}

// ---------------- gu GEMM device body: BM=256, 8 waves (512 threads) ----------------
// Block tile 256m x 64n per matrix (g,u share A). Wave grid 4m x 2n; wave tile
// 64m x 32n per matrix; acc 4x2 f32x4 per matrix (64 regs, same as BM=128).
// 24 KB staged per 32-k step -> 128 MFMA/step/block, B re-reads halved.
__device__ void gu_body_t(
    const f16* __restrict__ Xh, const f16* __restrict__ WsgT, const f16* __restrict__ WsuT,
    const f16* __restrict__ WgT, const f16* __restrict__ WuT,
    f16* __restrict__ A1s, f16* __restrict__ P,
    const float* __restrict__ sgate, const float* __restrict__ cw,
    const int* __restrict__ cnt, const int* __restrict__ tok,
    int bid, f16* As, f16* Bg, f16* Bu)
{
  const int tid = threadIdx.x, lane = tid&63, wave = tid>>6;   // wave 0..7
  const f16 *BgRow, *BuRow; f16* outp; const float* rs;
  int ldout, m0, n0;
  const f16 *gA0, *gA1;   // per-lane A source base (k offset 0)
  if (bid < 352){                       // shared expert: 88 n x 4 m of 256
    n0 = (bid % 88)*64; m0 = (bid / 88)*256;
    BgRow = WsgT + (size_t)n0*2048; BuRow = WsuT + (size_t)n0*2048;
    outp = A1s; rs = sgate; ldout = 5632;
    const int r0 = m0 + wave*32 + (lane>>2);
    gA0 = Xh + (size_t)r0*2048 + (lane&3)*8;
    gA1 = gA0 + (size_t)16*2048;
  } else {                              // routed: per-e 22 n x 4 m of 256, compacted
    bid -= 352;
    const int e = bid / 88, r = bid % 88;
    const int mt = r / 22;
    if (mt*256 >= cnt[e]) return;       // tile beyond routed-token count
    n0 = (r % 22)*64; m0 = mt*256;
    const size_t off = (size_t)e*1408*2048;
    BgRow = WgT + off + (size_t)n0*2048; BuRow = WuT + off + (size_t)n0*2048;
    outp = P + (size_t)e*1024*1408; rs = cw + e*1024; ldout = 1408;
    const int* tp = tok + e*1024 + m0;
    const int t0 = tp[wave*32 + (lane>>2)];
    const int t1 = tp[wave*32 + 16 + (lane>>2)];
    gA0 = Xh + (size_t)t0*2048 + (lane&3)*8;
    gA1 = Xh + (size_t)t1*2048 + (lane&3)*8;
  }
  const int wm = wave>>1, wn = wave&1, lr = lane&15, q = lane>>4;
  // B staging: waves 0-3 stage Bg rows wave*16..; waves 4-7 stage Bu rows (wave-4)*16..
  const int brbase = (wave & 3)*16;
  const f16* gB = ((wave < 4) ? BgRow : BuRow)
                + (size_t)(brbase + (lane>>2))*2048 + (lane&3)*8;
  f16* LB = ((wave < 4) ? Bg : Bu) + brbase*32;

  const f32x4 z4 = {0.f,0.f,0.f,0.f};
  f32x4 ag[4][2], au[4][2];
#pragma unroll
  for (int mi = 0; mi < 4; ++mi)
#pragma unroll
    for (int ni = 0; ni < 2; ++ni){ ag[mi][ni] = z4; au[mi][ni] = z4; }

  for (int k0 = 0; k0 < 2048; k0 += 32){
    __syncthreads();
    GLDS(gA0 + k0, As + (wave*32)*32);
    GLDS(gA1 + k0, As + (wave*32 + 16)*32);
    GLDS(gB  + k0, LB);
    __syncthreads();
    half8 af[4];
#pragma unroll
    for (int mi = 0; mi < 4; ++mi)
      af[mi] = *(const half8*)(As + (wm*64 + mi*16 + lr)*32 + q*8);
#pragma unroll
    for (int ni = 0; ni < 2; ++ni){
      const half8 bfg = *(const half8*)(Bg + (wn*32 + ni*16 + lr)*32 + q*8);
      const half8 bfu = *(const half8*)(Bu + (wn*32 + ni*16 + lr)*32 + q*8);
#pragma unroll
      for (int mi = 0; mi < 4; ++mi){
        ag[mi][ni] = __builtin_amdgcn_mfma_f32_16x16x32_f16(af[mi], bfg, ag[mi][ni], 0, 0, 0);
        au[mi][ni] = __builtin_amdgcn_mfma_f32_16x16x32_f16(af[mi], bfu, au[mi][ni], 0, 0, 0);
      }
    }
  }

  float rsv[4][4];
#pragma unroll
  for (int mi = 0; mi < 4; ++mi)
#pragma unroll
    for (int r = 0; r < 4; ++r)
      rsv[mi][r] = rs[m0 + wm*64 + mi*16 + q*4 + r];
#pragma unroll
  for (int mi = 0; mi < 4; ++mi)
#pragma unroll
    for (int ni = 0; ni < 2; ++ni)
#pragma unroll
      for (int r = 0; r < 4; ++r){
        const int row = m0 + wm*64 + mi*16 + q*4 + r;
        const int col = n0 + wn*32 + ni*16 + lr;
        const float g = ag[mi][ni][r];
        const float v = (g / (1.f + __expf(-g))) * au[mi][ni][r] * rsv[mi][r];
        outp[(size_t)row*ldout + col] = (f16)v;
      }
}

// ---------------- gu_fused: 512-thr; gu (1056) interleaved 1:4 with tcvt(Wd,Wsd) ----------------
// 5280 blocks: bid%5==0 -> gu block bid/5; else each 512-thr block transposes
// TWO 64x64 tiles (one per 256-thr half). 8448 tiles = 4224 pairs = 4*1056.
__global__ __launch_bounds__(512) void gu_fused(
    const f16* __restrict__ Xh, const f16* __restrict__ WsgT, const f16* __restrict__ WsuT,
    const f16* __restrict__ WgT, const f16* __restrict__ WuT,
    f16* __restrict__ A1s, f16* __restrict__ P,
    const float* __restrict__ sgate, const float* __restrict__ cw,
    const int* __restrict__ cnt, const int* __restrict__ tok,
    const void* Wd, const void* Wsd, f16* WdT, f16* WsdT, const int* flag)
{
  __shared__ __align__(16) char smbuf[24576];
  const int bid = blockIdx.x;
  const int g = bid/5, r = bid%5;
  if (r == 0){
    f16* As = (f16*)smbuf;                 // 256*32 f16 = 16384 B
    f16* Bg = (f16*)(smbuf + 16384);       // 64*32  f16 =  4096 B
    f16* Bu = (f16*)(smbuf + 20480);       // 64*32  f16 =  4096 B
    gu_body_t(Xh, WsgT, WsuT, WgT, WuT, A1s, P, sgate, cw, cnt, tok, g, As, Bg, Bu);
    return;
  }
  const int sub = threadIdx.x >> 8;        // 0 or 1 (two 256-thr halves)
  int idx = (4*g + (r-1))*2 + sub;         // 0..8447
  f16* Tt = (f16*)(smbuf + sub*9216);      // 2 x 64*TP f16 = 2 x 9216 B
  const void* S; f16* D; int K, N, nx;
  if (idx < 5632){ S = Wd; D = WdT; K = 11264; N = 2048; nx = 32; }
  else { idx -= 5632; S = Wsd; D = WsdT; K = 5632; N = 2048; nx = 32; }
  const int n0 = (idx % nx)*64, k0 = (idx / nx)*64;
  const int t = threadIdx.x & 255;
  if (*flag) tcvt64<true >(S, D, K, N, 0, n0, k0, Tt, t);
  else       tcvt64<false>(S, D, K, N, 0, n0, k0, Tt, t);
}

// ---------------- FULL: down GEMM (R0-proven body) ----------------
// z<8: routed expert z, K=1408, compacted rows (early-exit past cnt[z]).
// z=8,9: shared expert K-chunks of 2816.
__global__ __launch_bounds__(256) void down_gemm_t(
    const f16* __restrict__ Pm, const f16* __restrict__ A1s,
    const f16* __restrict__ WdT, const f16* __restrict__ WsdT,
    const int* __restrict__ cnt,
    float* __restrict__ downR, float* __restrict__ shp)
{
  __shared__ f16 As[128*32];
  __shared__ f16 Bs[128*32];
  const int z = blockIdx.z;
  const int m0 = blockIdx.y*128, n0 = blockIdx.x*128;
  const f16 *A, *B; int lda, ldk, KT; float* C;
  if (z < 8){
    if (m0 >= cnt[z]) return;
    A = Pm + (size_t)z*1024*1408 + (size_t)m0*1408; lda = 1408;
    B = WdT + (size_t)z*1408; ldk = 11264; KT = 44;
    C = downR + (size_t)z*1024*2048;
  } else {
    A = A1s + (size_t)(z-8)*2816 + (size_t)m0*5632; lda = 5632;
    B = WsdT + (size_t)(z-8)*2816; ldk = 5632; KT = 88;
    C = shp + (size_t)(z-8)*2097152;
  }
  const f16* Arow = A;
  const f16* Brow = B + (size_t)n0*ldk;
  const int tid = threadIdx.x, lane = tid&63, wave = tid>>6;
  const int wm = wave>>1, wn = wave&1, lr = lane&15, q = lane>>4;

  const f32x4 z4 = {0.f,0.f,0.f,0.f};
  f32x4 acc[4][4];
#pragma unroll
  for (int mi = 0; mi < 4; ++mi)
#pragma unroll
    for (int ni = 0; ni < 4; ++ni) acc[mi][ni] = z4;

  for (int kt = 0; kt < KT; ++kt){
    __syncthreads();
    stage_T128(Arow, lda, kt*32, As);
    stage_T128(Brow, ldk, kt*32, Bs);
    __syncthreads();
    half8 af[4], bf[4];
#pragma unroll
    for (int mi = 0; mi < 4; ++mi)
      af[mi] = *(const half8*)(As + (wm*64 + mi*16 + lr)*32 + q*8);
#pragma unroll
    for (int ni = 0; ni < 4; ++ni)
      bf[ni] = *(const half8*)(Bs + (wn*64 + ni*16 + lr)*32 + q*8);
#pragma unroll
    for (int ni = 0; ni < 4; ++ni)
#pragma unroll
      for (int mi = 0; mi < 4; ++mi)
        acc[mi][ni] = __builtin_amdgcn_mfma_f32_16x16x32_f16(af[mi], bf[ni], acc[mi][ni], 0, 0, 0);
  }
#pragma unroll
  for (int mi = 0; mi < 4; ++mi)
#pragma unroll
    for (int ni = 0; ni < 4; ++ni)
#pragma unroll
      for (int r = 0; r < 4; ++r){
        const int row = m0 + wm*64 + mi*16 + q*4 + r;
        const int col = n0 + wn*64 + ni*16 + lr;
        C[(size_t)row*2048 + col] = acc[mi][ni][r];
      }
}

// ---------------- FULL: final = 0.5*(sh0+sh1 + gather of token's 4 rows) ----------------
__global__ __launch_bounds__(256) void final_g(
    const float4* __restrict__ sh0, const float4* __restrict__ sh1,
    const float4* __restrict__ downR, const int* __restrict__ inv,
    void* __restrict__ out, const int* __restrict__ flag){
  const int t = blockIdx.x;
  const int4 iv = *(const int4*)(inv + t*4);
  const int idx[4] = {iv.x, iv.y, iv.z, iv.w};
#pragma unroll
  for (int jj = 0; jj < 2; ++jj){
    const int j = threadIdx.x + jj*256;         // float4 index within 512-wide row
    const size_t b = (size_t)t*512 + j;
    const float4 a = sh0[b], c = sh1[b];
    float v0 = a.x + c.x, v1 = a.y + c.y, v2 = a.z + c.z, v3 = a.w + c.w;
#pragma unroll
    for (int k = 0; k < 4; ++k){
      if (idx[k] >= 0){
        const float4 d = downR[(size_t)idx[k]*512 + j];
        v0 += d.x; v1 += d.y; v2 += d.z; v3 += d.w;
      }
    }
    v0 *= 0.5f; v1 *= 0.5f; v2 *= 0.5f; v3 *= 0.5f;
    if (*flag){
      float4 o; o.x=v0; o.y=v1; o.z=v2; o.w=v3;
      ((float4*)out)[b] = o;
    } else {
      uint2 o;
      o.x = (uint32_t)f2b(v0) | ((uint32_t)f2b(v1) << 16);
      o.y = (uint32_t)f2b(v2) | ((uint32_t)f2b(v3) << 16);
      ((uint2*)out)[b] = o;
    }
  }
}

// ================= FALLBACK (round-3) kernels =================
#define LDBT 40
#define ABUF 4096
#define BBUF 2560
struct BR { float v[8]; };
template<bool F32>
__device__ __forceinline__ void loadB(const void* __restrict__ B, size_t ldb, int k0, int n0, BR& r){
  const int t = threadIdx.x, c = t&63, kg = t>>6;
  if (F32){
    const float* p = (const float*)B + (size_t)(k0 + kg*8)*ldb + (n0 + c);
#pragma unroll
    for (int j = 0; j < 8; ++j) r.v[j] = p[(size_t)j*ldb];
  } else {
    const u16* p = (const u16*)B + (size_t)(k0 + kg*8)*ldb + (n0 + c);
#pragma unroll
    for (int j = 0; j < 8; ++j) r.v[j] = b2f(p[(size_t)j*ldb]);
  }
}
__device__ __forceinline__ void storeB(const BR& r, f16* BT){
  const int t = threadIdx.x, c = t&63, kg = t>>6;
  half8 h;
#pragma unroll
  for (int j = 0; j < 8; ++j) h[j] = (f16)r.v[j];
  *(half8*)(BT + c*LDBT + kg*8) = h;
}
template<bool F32>
__device__ void gu_body_r(const f16* __restrict__ Arow, const void* __restrict__ Bgp,
                          const void* __restrict__ Bup, f16* __restrict__ outp,
                          const float* __restrict__ rs, int rs_stride,
                          int ldb, int ldout, int m0, int n0,
                          f16* As, f16* BgT, f16* BuT)
{
  const int tid = threadIdx.x, lane = tid&63, wave = tid>>6;
  const int wm = wave>>1, wn = wave&1, lr = lane&15, q = lane>>4;
  const f32x4 z4 = {0.f,0.f,0.f,0.f};
  f32x4 ag[4][2], au[4][2];
#pragma unroll
  for (int mi = 0; mi < 4; ++mi)
#pragma unroll
    for (int ni = 0; ni < 2; ++ni){ ag[mi][ni] = z4; au[mi][ni] = z4; }
  const int KT = 64;
  BR rg, ru;
  loadB<F32>(Bgp, ldb, 0, n0, rg);
  loadB<F32>(Bup, ldb, 0, n0, ru);
  storeB(rg, BgT); storeB(ru, BuT);
  stage_T128(Arow, 2048, 0, As);
  loadB<F32>(Bgp, ldb, 32, n0, rg);
  loadB<F32>(Bup, ldb, 32, n0, ru);
  __syncthreads();
  for (int kt = 0; kt < KT; ++kt){
    const int cur = kt&1, nxt = cur^1;
    if (kt+1 < KT){
      storeB(rg, BgT + nxt*BBUF);
      storeB(ru, BuT + nxt*BBUF);
      stage_T128(Arow, 2048, (kt+1)*32, As + nxt*ABUF);
    }
    if (kt+2 < KT){
      loadB<F32>(Bgp, ldb, (kt+2)*32, n0, rg);
      loadB<F32>(Bup, ldb, (kt+2)*32, n0, ru);
    }
    const f16* Ac = As + cur*ABUF;
    const f16* Bgc = BgT + cur*BBUF;
    const f16* Buc = BuT + cur*BBUF;
    half8 af[4];
#pragma unroll
    for (int mi = 0; mi < 4; ++mi)
      af[mi] = *(const half8*)(Ac + (wm*64 + mi*16 + lr)*32 + q*8);
#pragma unroll
    for (int ni = 0; ni < 2; ++ni){
      const half8 bfg = *(const half8*)(Bgc + (wn*32 + ni*16 + lr)*LDBT + q*8);
      const half8 bfu = *(const half8*)(Buc + (wn*32 + ni*16 + lr)*LDBT + q*8);
#pragma unroll
      for (int mi = 0; mi < 4; ++mi){
        ag[mi][ni] = __builtin_amdgcn_mfma_f32_16x16x32_f16(af[mi], bfg, ag[mi][ni], 0, 0, 0);
        au[mi][ni] = __builtin_amdgcn_mfma_f32_16x16x32_f16(af[mi], bfu, au[mi][ni], 0, 0, 0);
      }
    }
    __syncthreads();
  }
  float rsv[4][4];
#pragma unroll
  for (int mi = 0; mi < 4; ++mi)
#pragma unroll
    for (int r = 0; r < 4; ++r)
      rsv[mi][r] = rs[(size_t)(m0 + wm*64 + mi*16 + q*4 + r)*rs_stride];
#pragma unroll
  for (int mi = 0; mi < 4; ++mi)
#pragma unroll
    for (int ni = 0; ni < 2; ++ni)
#pragma unroll
      for (int r = 0; r < 4; ++r){
        const int row = m0 + wm*64 + mi*16 + q*4 + r;
        const int col = n0 + wn*32 + ni*16 + lr;
        const float g = ag[mi][ni][r];
        const float v = (g / (1.f + __expf(-g))) * au[mi][ni][r] * rsv[mi][r];
        outp[(size_t)row*ldout + col] = (f16)v;
      }
}
__global__ __launch_bounds__(256) void gu_gemm_r(
    const f16* __restrict__ Xh, const void* Wsg, const void* Wsu,
    const void* Wg, const void* Wu, f16* __restrict__ A1s, f16* __restrict__ P,
    const float* __restrict__ sgate, const float* __restrict__ combine, const int* flag)
{
  __shared__ f16 As[2*ABUF];
  __shared__ f16 BgT[2*BBUF];
  __shared__ f16 BuT[2*BBUF];
  const bool f32v = (*flag != 0);
  int bid = blockIdx.x;
  const void *Bg, *Bu; f16* outp; const float* rs;
  int rs_stride, ldb, ldout, m0, n0;
  if (bid < 704){
    n0 = (bid % 88)*64; m0 = (bid / 88)*128;
    Bg = Wsg; Bu = Wsu; outp = A1s; rs = sgate;
    rs_stride = 1; ldb = 5632; ldout = 5632;
  } else {
    bid -= 704;
    const int e = bid / 176, r = bid % 176;
    n0 = (r % 22)*64; m0 = (r / 22)*128;
    const size_t off = (size_t)e*2048*1408;
    Bg = f32v ? (const void*)((const float*)Wg + off) : (const void*)((const u16*)Wg + off);
    Bu = f32v ? (const void*)((const float*)Wu + off) : (const void*)((const u16*)Wu + off);
    outp = P + (size_t)e*1408; rs = combine + e;
    rs_stride = 8; ldb = 1408; ldout = 11264;
  }
  const f16* Arow = Xh + (size_t)m0*2048;
  if (f32v) gu_body_r<true >(Arow, Bg, Bu, outp, rs, rs_stride, ldb, ldout, m0, n0, As, BgT, BuT);
  else      gu_body_r<false>(Arow, Bg, Bu, outp, rs, rs_stride, ldb, ldout, m0, n0, As, BgT, BuT);
}
template<bool F32>
__device__ void down_body_r(const f16* __restrict__ Arow, int lda, const void* __restrict__ B,
                            float* __restrict__ C, int m0, int n0, f16* As, f16* BT)
{
  const int tid = threadIdx.x, lane = tid&63, wave = tid>>6;
  const int wm = wave>>1, wn = wave&1, lr = lane&15, q = lane>>4;
  const f32x4 z4 = {0.f,0.f,0.f,0.f};
  f32x4 acc[4][2];
#pragma unroll
  for (int mi = 0; mi < 4; ++mi)
#pragma unroll
    for (int ni = 0; ni < 2; ++ni) acc[mi][ni] = z4;
  const int KT = 176;
  BR rb;
  loadB<F32>(B, 2048, 0, n0, rb);
  storeB(rb, BT);
  stage_T128(Arow, lda, 0, As);
  loadB<F32>(B, 2048, 32, n0, rb);
  __syncthreads();
  for (int kt = 0; kt < KT; ++kt){
    const int cur = kt&1, nxt = cur^1;
    if (kt+1 < KT){
      storeB(rb, BT + nxt*BBUF);
      stage_T128(Arow, lda, (kt+1)*32, As + nxt*ABUF);
    }
    if (kt+2 < KT) loadB<F32>(B, 2048, (kt+2)*32, n0, rb);
    const f16* Ac = As + cur*ABUF;
    const f16* Bc = BT + cur*BBUF;
    half8 af[4];
#pragma unroll
    for (int mi = 0; mi < 4; ++mi)
      af[mi] = *(const half8*)(Ac + (wm*64 + mi*16 + lr)*32 + q*8);
#pragma unroll
    for (int ni = 0; ni < 2; ++ni){
      const half8 bf = *(const half8*)(Bc + (wn*32 + ni*16 + lr)*LDBT + q*8);
#pragma unroll
      for (int mi = 0; mi < 4; ++mi)
        acc[mi][ni] = __builtin_amdgcn_mfma_f32_16x16x32_f16(af[mi], bf, acc[mi][ni], 0, 0, 0);
    }
    __syncthreads();
  }
#pragma unroll
  for (int mi = 0; mi < 4; ++mi)
#pragma unroll
    for (int ni = 0; ni < 2; ++ni)
#pragma unroll
      for (int r = 0; r < 4; ++r){
        const int row = m0 + wm*64 + mi*16 + q*4 + r;
        const int col = n0 + wn*32 + ni*16 + lr;
        C[(size_t)row*2048 + col] = acc[mi][ni][r];
      }
}
__global__ __launch_bounds__(256) void down_gemm_r(
    const f16* __restrict__ Pm, const f16* __restrict__ A1s,
    const void* Wd, const void* Wsd,
    float* __restrict__ c0, float* __restrict__ c1, float* __restrict__ c2, const int* flag)
{
  __shared__ f16 As[2*ABUF];
  __shared__ f16 BT[2*BBUF];
  const int z = blockIdx.z;
  const bool f32v = (*flag != 0);
  const f16* A; const void* B; float* C; int lda;
  if (z == 0){ A = Pm; B = Wd; C = c0; lda = 11264; }
  else if (z == 1){
    A = Pm + 5632;
    B = f32v ? (const void*)((const float*)Wd + (size_t)5632*2048)
             : (const void*)((const u16*)Wd + (size_t)5632*2048);
    C = c1; lda = 11264;
  } else { A = A1s; B = Wsd; C = c2; lda = 5632; }
  const int m0 = blockIdx.y*128, n0 = blockIdx.x*64;
  const f16* Arow = A + (size_t)m0*lda;
  if (f32v) down_body_r<true >(Arow, lda, B, C, m0, n0, As, BT);
  else      down_body_r<false>(Arow, lda, B, C, m0, n0, As, BT);
}
__global__ __launch_bounds__(256) void final3(
    const float4* __restrict__ b0, const float4* __restrict__ b1, const float4* __restrict__ b2,
    void* __restrict__ out, const int* flag, int n4){
  const int i = blockIdx.x*256 + threadIdx.x;
  if (i >= n4) return;
  const float4 a = b0[i], b = b1[i], c = b2[i];
  const float v0 = 0.5f*(a.x + b.x + c.x);
  const float v1 = 0.5f*(a.y + b.y + c.y);
  const float v2 = 0.5f*(a.z + b.z + c.z);
  const float v3 = 0.5f*(a.w + b.w + c.w);
  if (*flag){
    float4 o; o.x=v0; o.y=v1; o.z=v2; o.w=v3;
    ((float4*)out)[i] = o;
  } else {
    uint2 o;
    o.x = (uint32_t)f2b(v0) | ((uint32_t)f2b(v1) << 16);
    o.y = (uint32_t)f2b(v2) | ((uint32_t)f2b(v3) << 16);
    ((uint2*)out)[i] = o;
  }
}

// ================= host =================
extern "C" void kernel_launch(void* const* d_in, const int* in_sizes, int n_in,
                              void* d_out, int out_size, void* d_ws, size_t ws_size,
                              hipStream_t stream)
{
  (void)in_sizes; (void)n_in; (void)out_size;
  const void* x   = d_in[0];
  const void* Wg  = d_in[1];
  const void* Wu  = d_in[2];
  const void* Wd  = d_in[3];
  const void* Wsg = d_in[4];
  const void* Wsu = d_in[5];
  const void* Wsd = d_in[6];
  const void* Wr  = d_in[7];
  const void* Wxg = d_in[8];

  char* ws = (char*)d_ws;
  size_t off = 0;
  auto alloc = [&](size_t bytes)->char*{
    char* p = ws + off; off = (off + bytes + 255) & ~(size_t)255; return p;
  };
  float* combine = (float*)alloc(32768);
  float* sgate   = (float*)alloc(4096);
  int*   flag    = (int*)  alloc(4096);
  int*   cnt     = (int*)  alloc(4096);
  int*   tok     = (int*)  alloc(8*1024*4);
  float* cw      = (float*)alloc(8*1024*4);
  int*   inv     = (int*)  alloc(1024*4*4);
  f16*   Xh      = (f16*)  alloc((size_t)1024*2048*2);
  f16*   A1s     = (f16*)  alloc((size_t)1024*5632*2);
  f16*   P       = (f16*)  alloc((size_t)8*1024*1408*2);        // per-expert compacted
  float* shp     = (float*)alloc((size_t)3*2097152*4);          // 2 shared partials (+1 fallback)
  float* downR   = (float*)alloc((size_t)8*1024*2048*4);        // routed down, compacted fp32
  f16*   WsgT    = (f16*)  alloc((size_t)5632*2048*2);
  f16*   WsuT    = (f16*)  alloc((size_t)5632*2048*2);
  f16*   WgT     = (f16*)  alloc((size_t)8*1408*2048*2);
  f16*   WuT     = (f16*)  alloc((size_t)8*1408*2048*2);
  f16*   WdT     = (f16*)  alloc((size_t)2048*11264*2);
  f16*   WsdT    = (f16*)  alloc((size_t)2048*5632*2);
  const size_t NEED_FULL = off;

  detect_kernel<<<dim3(1), dim3(64), 0, stream>>>((const uint32_t*)x, flag);
  router_conv<<<dim3(1024), dim3(256), 0, stream>>>(x, Wr, Wxg, Xh, combine, sgate, flag);

  if (ws_size >= NEED_FULL){
    prep_gu<<<dim3(16897), dim3(256), 0, stream>>>(
        Wsg, Wsu, Wg, Wu, WsgT, WsuT, WgT, WuT,
        combine, cnt, tok, cw, inv, flag);
    gu_fused<<<dim3(5280), dim3(512), 0, stream>>>(
        Xh, WsgT, WsuT, WgT, WuT, A1s, P, sgate, cw, cnt, tok,
        Wd, Wsd, WdT, WsdT, flag);
    down_gemm_t<<<dim3(16, 8, 10), dim3(256), 0, stream>>>(P, A1s, WdT, WsdT, cnt, downR, shp);
    final_g<<<dim3(1024), dim3(256), 0, stream>>>(
        (const float4*)shp, (const float4*)(shp + 2097152), (const float4*)downR,
        inv, d_out, flag);
  } else {
    // fallback: round-3 register-staging path (needs only ~65 MB: up through shp)
    float* b0 = shp;
    float* b1 = shp + 2097152;
    float* b2 = shp + 2*2097152;
    gu_gemm_r<<<dim3(2112), dim3(256), 0, stream>>>(
        Xh, Wsg, Wsu, Wg, Wu, A1s, P, sgate, combine, flag);
    down_gemm_r<<<dim3(32, 8, 3), dim3(256), 0, stream>>>(P, A1s, Wd, Wsd, b0, b1, b2, flag);
    final3<<<dim3(2048), dim3(256), 0, stream>>>(
        (const float4*)b0, (const float4*)b1, (const float4*)b2, d_out, flag, 524288);
  }
}

// Round 10
// 670.812 us; speedup vs baseline: 1.0069x; 1.0069x over previous
//
#include <hip/hip_runtime.h>
#include <cstdint>
#include <cstddef>

// Qwen2 MoE MLP block. T=1024 H=2048 I=1408 SI=5632 E=8 K=4, scale=0.5.
// fp32 interface (runtime-detected, bf16 fallback). Internal: f16, fp32 accum.
//
// FULL path (ws >= ~340MB), 5 launches:
//   router_conv2 (inline dtype detect + router + X->f16; block 0 writes flag) ->
//   prep_gu  : tcvt(Wsg,Wsu,Wg,Wu) 16896 blocks + compact as block 16896
//   gu_fused : gu GEMM (2112 logical blocks, R0-proven body) INTERLEAVED 1:4
//              with tcvt(Wd,Wsd) blocks -> down-weight transpose overlaps the
//              latency-bound GEMM (validated: -17us in R8)
//   down_gemm_t: R0-proven body; per-expert K=1408 compacted + 2 shared chunks
//   final_g  : out[t] = 0.5*(sh0+sh1 + sum of token's 4 compacted rows)
// FALLBACK path (small ws): round-3 register-staging kernels (dense).

typedef unsigned short u16;
typedef _Float16 f16;
typedef __attribute__((ext_vector_type(8))) _Float16 half8;
typedef __attribute__((ext_vector_type(4))) float f32x4;

#define GLDS(g, l) __builtin_amdgcn_global_load_lds(                          \
    (const __attribute__((address_space(1))) void*)(g),                       \
    (__attribute__((address_space(3))) void*)(l), 16, 0, 0)

__device__ __forceinline__ float b2f(u16 u){ return __uint_as_float(((uint32_t)u)<<16); }
__device__ __forceinline__ u16 f2b(float f){
  uint32_t x = __float_as_uint(f);
  return (u16)((x + 0x7fffu + ((x>>16)&1u)) >> 16);   // RNE
}

// ---------------- dtype detection (fallback path only) ----------------
__global__ __launch_bounds__(64) void detect_kernel(const uint32_t* __restrict__ X,
                                                    int* __restrict__ flag){
  const int lane = threadIdx.x;
  int cnt = 0;
  for (int i = lane; i < 256; i += 64){
    const uint32_t e = (X[i] >> 23) & 0xffu;
    cnt += (e >= 90u && e <= 160u) ? 1 : 0;
  }
#pragma unroll
  for (int off = 32; off > 0; off >>= 1) cnt += __shfl_xor(cnt, off, 64);
  if (lane == 0) *flag = (cnt > 128) ? 1 : 0;
}

// ---------------- fused router + X->f16 convert ----------------
template<bool F32>
__device__ void router_conv_body(const void* X, const void* Wr, const void* Wxg,
                                 f16* __restrict__ Xh, float* __restrict__ combine,
                                 float* __restrict__ sgate, float (*red)[9]){
  const int t = blockIdx.x, tid = threadIdx.x, lane = tid&63, wave = tid>>6;
  const int h0 = tid*8;
  float xv[8], gv[8];
  if (F32){
    const float* xp = (const float*)X + (size_t)t*2048 + h0;
    const float4 a = *(const float4*)xp, b = *(const float4*)(xp+4);
    xv[0]=a.x; xv[1]=a.y; xv[2]=a.z; xv[3]=a.w;
    xv[4]=b.x; xv[5]=b.y; xv[6]=b.z; xv[7]=b.w;
    const float* gp = (const float*)Wxg + h0;
    const float4 c = *(const float4*)gp, d = *(const float4*)(gp+4);
    gv[0]=c.x; gv[1]=c.y; gv[2]=c.z; gv[3]=c.w;
    gv[4]=d.x; gv[5]=d.y; gv[6]=d.z; gv[7]=d.w;
  } else {
    union { uint4 v; u16 s[8]; } xr, gr;
    xr.v = *(const uint4*)((const u16*)X + (size_t)t*2048 + h0);
    gr.v = *(const uint4*)((const u16*)Wxg + h0);
#pragma unroll
    for (int q = 0; q < 8; ++q){ xv[q] = b2f(xr.s[q]); gv[q] = b2f(gr.s[q]); }
  }
  half8 h8;
#pragma unroll
  for (int j = 0; j < 8; ++j) h8[j] = (f16)xv[j];
  *(half8*)(Xh + (size_t)t*2048 + h0) = h8;

  float acc[8] = {0,0,0,0,0,0,0,0};
  float ag = 0.f;
#pragma unroll
  for (int jj = 0; jj < 8; ++jj){
    const int h = h0 + jj;
    float w[8];
    if (F32){
      const float* wp = (const float*)Wr + (size_t)h*8;
      const float4 w0 = *(const float4*)wp, w1 = *(const float4*)(wp+4);
      w[0]=w0.x; w[1]=w0.y; w[2]=w0.z; w[3]=w0.w;
      w[4]=w1.x; w[5]=w1.y; w[6]=w1.z; w[7]=w1.w;
    } else {
      union { uint4 v; u16 s[8]; } wv;
      wv.v = *(const uint4*)((const u16*)Wr + (size_t)h*8);
#pragma unroll
      for (int q = 0; q < 8; ++q) w[q] = b2f(wv.s[q]);
    }
#pragma unroll
    for (int e = 0; e < 8; ++e) acc[e] += xv[jj] * w[e];
    ag += xv[jj] * gv[jj];
  }
#pragma unroll
  for (int off = 32; off > 0; off >>= 1){
#pragma unroll
    for (int e = 0; e < 8; ++e) acc[e] += __shfl_xor(acc[e], off, 64);
    ag += __shfl_xor(ag, off, 64);
  }
  if (lane == 0){
#pragma unroll
    for (int e = 0; e < 8; ++e) red[wave][e] = acc[e];
    red[wave][8] = ag;
  }
  __syncthreads();
  if (tid == 0){
    float a[8], g = 0.f;
#pragma unroll
    for (int e = 0; e < 8; ++e) a[e] = red[0][e] + red[1][e] + red[2][e] + red[3][e];
    g = red[0][8] + red[1][8] + red[2][8] + red[3][8];
    float m = a[0];
#pragma unroll
    for (int e = 1; e < 8; ++e) m = fmaxf(m, a[e]);
    float p[8]; float s = 0.f;
#pragma unroll
    for (int e = 0; e < 8; ++e){ p[e] = __expf(a[e]-m); s += p[e]; }
    const float inv = 1.f/s;
#pragma unroll
    for (int e = 0; e < 8; ++e) p[e] *= inv;
#pragma unroll
    for (int e = 0; e < 8; ++e){
      int cnt = 0;
#pragma unroll
      for (int j = 0; j < 8; ++j)
        cnt += (p[j] > p[e]) || (p[j] == p[e] && j < e);
      combine[(size_t)t*8 + e] = (cnt < 4) ? p[e] : 0.f;
    }
    sgate[t] = 1.f/(1.f + __expf(-g));
  }
}
// fallback-path variant (flag precomputed by detect_kernel)
__global__ __launch_bounds__(256) void router_conv(const void* X, const void* Wr, const void* Wxg,
                                                   f16* Xh, float* combine, float* sgate,
                                                   const int* flag){
  __shared__ float red[4][9];
  if (*flag) router_conv_body<true >(X, Wr, Wxg, Xh, combine, sgate, red);
  else       router_conv_body<false>(X, Wr, Wxg, Xh, combine, sgate, red);
}
// full-path variant: inline per-block dtype detect; block 0 publishes flag.
__global__ __launch_bounds__(256) void router_conv2(const void* X, const void* Wr, const void* Wxg,
                                                    f16* Xh, float* combine, float* sgate,
                                                    int* flag){
  __shared__ float red[4][9];
  __shared__ int sc[4];
  const int tid = threadIdx.x, lane = tid&63, wave = tid>>6;
  bool f32v;
  {
    const uint32_t v = ((const uint32_t*)X)[tid];
    const uint32_t e = (v >> 23) & 0xffu;
    const unsigned long long b = __ballot(e >= 90u && e <= 160u);
    if (lane == 0) sc[wave] = (int)__popcll(b);
    __syncthreads();
    f32v = (sc[0] + sc[1] + sc[2] + sc[3]) > 128;
    if (blockIdx.x == 0 && tid == 0) *flag = f32v ? 1 : 0;
    __syncthreads();
  }
  if (f32v) router_conv_body<true >(X, Wr, Wxg, Xh, combine, sgate, red);
  else      router_conv_body<false>(X, Wr, Wxg, Xh, combine, sgate, red);
}

// ---------------- routed-token compaction (256-thread device body) ----------------
__device__ void compact256(const float* __restrict__ combine, int* __restrict__ cnt,
                           int* __restrict__ tok, float* __restrict__ cw,
                           int* __restrict__ inv, int* lc){
  const int tid = threadIdx.x;
  if (tid < 8) lc[tid] = 0;
  __syncthreads();
#pragma unroll
  for (int s = 0; s < 4; ++s){
    const int t = s*256 + tid;
    int k = 0;
#pragma unroll
    for (int e = 0; e < 8; ++e){
      const float v = combine[(size_t)t*8 + e];
      if (v > 0.f){
        const int p = atomicAdd(&lc[e], 1);
        tok[e*1024 + p] = t;
        cw [e*1024 + p] = v;
        if (k < 4) inv[t*4 + k] = e*1024 + p;
        ++k;
      }
    }
    for (; k < 4; ++k) inv[t*4 + k] = -1;
  }
  __syncthreads();
#pragma unroll
  for (int e = 0; e < 8; ++e)
    for (int i = tid; i < 1024; i += 256)
      if (i >= lc[e]){ tok[e*1024 + i] = 0; cw[e*1024 + i] = 0.f; }
  if (tid < 8) cnt[tid] = lc[tid];
}

// ---------------- weight transpose+convert (64k x 64n tiles, 9.2KB f16 LDS) ----------------
#define TP 72   // LDS tile row stride (f16): 144B -> 16B-aligned half8 reads
template<bool F32>
__device__ void tcvt64(const void* S, f16* __restrict__ Dm, int K, int N,
                       size_t soff, int n0, int k0, f16* Tt){
  const int t = threadIdx.x;
  const int kr = t >> 4, nc = (t & 15)*4;
#pragma unroll
  for (int p = 0; p < 4; ++p){
    const int kk = p*16 + kr;
    float v0, v1, v2, v3;
    if (F32){
      const float* Sm = (const float*)S + soff;
      const float4 v = *(const float4*)(Sm + (size_t)(k0+kk)*N + n0 + nc);
      v0=v.x; v1=v.y; v2=v.z; v3=v.w;
    } else {
      const u16* Sm = (const u16*)S + soff;
      union { uint2 u; u16 s[4]; } r;
      r.u = *(const uint2*)(Sm + (size_t)(k0+kk)*N + n0 + nc);
      v0=b2f(r.s[0]); v1=b2f(r.s[1]); v2=b2f(r.s[2]); v3=b2f(r.s[3]);
    }
    Tt[(nc+0)*TP + kk] = (f16)v0;
    Tt[(nc+1)*TP + kk] = (f16)v1;
    Tt[(nc+2)*TP + kk] = (f16)v2;
    Tt[(nc+3)*TP + kk] = (f16)v3;
  }
  __syncthreads();
  const int nr = t >> 3, kc = (t & 7)*8;
#pragma unroll
  for (int p = 0; p < 2; ++p){
    const int n = p*32 + nr;
    const half8 v = *(const half8*)(Tt + n*TP + kc);
    *(half8*)(Dm + (size_t)(n0+n)*K + k0 + kc) = v;
  }
}

// ---------------- prep_gu: tcvt(Wsg,Wsu,Wg,Wu) + compact as last block ----------------
// segments (64x64 tiles): Wsg 2816 | Wsu 2816 | Wg 8*704 | Wu 8*704 => 16896,
// block 16896 = compact (overlaps with the transpose stream).
__global__ __launch_bounds__(256) void prep_gu(
    const void* Wsg, const void* Wsu, const void* Wg, const void* Wu,
    f16* WsgT, f16* WsuT, f16* WgT, f16* WuT,
    const float* combine, int* cnt, int* tok, float* cw, int* inv,
    const int* flag){
  __shared__ f16 Tt[64*TP];
  int bid = blockIdx.x;
  if (bid == 16896){
    compact256(combine, cnt, tok, cw, inv, (int*)Tt);
    return;
  }
  const void* S; f16* D; int K, N, nx; size_t soff = 0;
  if (bid < 2816){ S = Wsg; D = WsgT; K = 2048; N = 5632; nx = 88; }
  else if (bid < 5632){ bid -= 2816; S = Wsu; D = WsuT; K = 2048; N = 5632; nx = 88; }
  else if (bid < 11264){
    bid -= 5632; const int z = bid/704; bid -= z*704;
    soff = (size_t)z*2048*1408;
    S = Wg; D = WgT + soff; K = 2048; N = 1408; nx = 22;
  } else {
    bid -= 11264; const int z = bid/704; bid -= z*704;
    soff = (size_t)z*2048*1408;
    S = Wu; D = WuT + soff; K = 2048; N = 1408; nx = 22;
  }
  const int n0 = (bid % nx)*64, k0 = (bid / nx)*64;
  if (*flag) tcvt64<true >(S, D, K, N, soff, n0, k0, Tt);
  else       tcvt64<false>(S, D, K, N, soff, n0, k0, Tt);
}

// ---------------- async staging (f16, k-contiguous rows) ----------------
__device__ __forceinline__ void stage_T128(const f16* __restrict__ Row, int ld, int k0, f16* Ls){
  const int tid = threadIdx.x, wave = tid>>6, lane = tid&63;
#pragma unroll
  for (int i = 0; i < 2; ++i){
    const int rbase = i*64 + wave*16;
    const f16* g = Row + (size_t)(rbase + (lane>>2))*ld + (k0 + (lane&3)*8);
    GLDS(g, Ls + rbase*32);
  }
}
__device__ __forceinline__ void stage_T64(const f16* __restrict__ Row, int ld, int k0, f16* Ls){
  const int tid = threadIdx.x, wave = tid>>6, lane = tid&63;
  const int rbase = wave*16;
  const f16* g = Row + (size_t)(rbase + (lane>>2))*ld + (k0 + (lane&3)*8);
  GLDS(g, Ls + rbase*32);
}

// ---------------- gu GEMM device body (R0-proven, 16KB LDS) ----------------
__device__ void gu_body_t(
    const f16* __restrict__ Xh, const f16* __restrict__ WsgT, const f16* __restrict__ WsuT,
    const f16* __restrict__ WgT, const f16* __restrict__ WuT,
    f16* __restrict__ A1s, f16* __restrict__ P,
    const float* __restrict__ sgate, const float* __restrict__ cw,
    const int* __restrict__ cnt, const int* __restrict__ tok,
    int bid, f16* As, f16* Bg, f16* Bu)
{
  const int tid = threadIdx.x, lane = tid&63, wave = tid>>6;
  const f16 *BgRow, *BuRow; f16* outp; const float* rs;
  int ldout, m0, n0;
  const f16 *gA0, *gA1;   // per-lane A source base (k offset 0)
  if (bid < 704){                       // shared expert: N=5632
    n0 = (bid % 88)*64; m0 = (bid / 88)*128;
    BgRow = WsgT + (size_t)n0*2048; BuRow = WsuT + (size_t)n0*2048;
    outp = A1s; rs = sgate; ldout = 5632;
    const int r0 = m0 + wave*16 + (lane>>2);
    gA0 = Xh + (size_t)r0*2048 + (lane&3)*8;
    gA1 = gA0 + (size_t)64*2048;
  } else {                              // routed experts: per-e N=1408, compacted rows
    bid -= 704;
    const int e = bid / 176, r = bid % 176;
    const int mt = r / 22;
    if (mt*128 >= cnt[e]) return;       // tile beyond routed-token count
    n0 = (r % 22)*64; m0 = mt*128;
    const size_t off = (size_t)e*1408*2048;
    BgRow = WgT + off + (size_t)n0*2048; BuRow = WuT + off + (size_t)n0*2048;
    outp = P + (size_t)e*1024*1408; rs = cw + e*1024; ldout = 1408;
    const int* tp = tok + e*1024 + m0;
    const int t0 = tp[wave*16 + (lane>>2)];
    const int t1 = tp[64 + wave*16 + (lane>>2)];
    gA0 = Xh + (size_t)t0*2048 + (lane&3)*8;
    gA1 = Xh + (size_t)t1*2048 + (lane&3)*8;
  }
  const int wm = wave>>1, wn = wave&1, lr = lane&15, q = lane>>4;

  const f32x4 z4 = {0.f,0.f,0.f,0.f};
  f32x4 ag[4][2], au[4][2];
#pragma unroll
  for (int mi = 0; mi < 4; ++mi)
#pragma unroll
    for (int ni = 0; ni < 2; ++ni){ ag[mi][ni] = z4; au[mi][ni] = z4; }

  for (int k0 = 0; k0 < 2048; k0 += 32){
    __syncthreads();
    GLDS(gA0 + k0, As + wave*512);
    GLDS(gA1 + k0, As + 2048 + wave*512);
    stage_T64(BgRow, 2048, k0, Bg);
    stage_T64(BuRow, 2048, k0, Bu);
    __syncthreads();
    half8 af[4];
#pragma unroll
    for (int mi = 0; mi < 4; ++mi)
      af[mi] = *(const half8*)(As + (wm*64 + mi*16 + lr)*32 + q*8);
#pragma unroll
    for (int ni = 0; ni < 2; ++ni){
      const half8 bfg = *(const half8*)(Bg + (wn*32 + ni*16 + lr)*32 + q*8);
      const half8 bfu = *(const half8*)(Bu + (wn*32 + ni*16 + lr)*32 + q*8);
#pragma unroll
      for (int mi = 0; mi < 4; ++mi){
        ag[mi][ni] = __builtin_amdgcn_mfma_f32_16x16x32_f16(af[mi], bfg, ag[mi][ni], 0, 0, 0);
        au[mi][ni] = __builtin_amdgcn_mfma_f32_16x16x32_f16(af[mi], bfu, au[mi][ni], 0, 0, 0);
      }
    }
  }

  float rsv[4][4];
#pragma unroll
  for (int mi = 0; mi < 4; ++mi)
#pragma unroll
    for (int r = 0; r < 4; ++r)
      rsv[mi][r] = rs[m0 + wm*64 + mi*16 + q*4 + r];
#pragma unroll
  for (int mi = 0; mi < 4; ++mi)
#pragma unroll
    for (int ni = 0; ni < 2; ++ni)
#pragma unroll
      for (int r = 0; r < 4; ++r){
        const int row = m0 + wm*64 + mi*16 + q*4 + r;
        const int col = n0 + wn*32 + ni*16 + lr;
        const float g = ag[mi][ni][r];
        const float v = (g / (1.f + __expf(-g))) * au[mi][ni][r] * rsv[mi][r];
        outp[(size_t)row*ldout + col] = (f16)v;
      }
}

// ---------------- gu_fused: gu GEMM interleaved 1:4 with tcvt(Wd,Wsd) ----------------
// 10560 blocks: bid%5==0 -> gu block bid/5 (2112); else tcvt idx 4*(bid/5)+(bid%5-1)
// (8448 = Wd 5632 + Wsd 2816). The streaming transpose uses gu's idle HBM BW.
__global__ __launch_bounds__(256) void gu_fused(
    const f16* __restrict__ Xh, const f16* __restrict__ WsgT, const f16* __restrict__ WsuT,
    const f16* __restrict__ WgT, const f16* __restrict__ WuT,
    f16* __restrict__ A1s, f16* __restrict__ P,
    const float* __restrict__ sgate, const float* __restrict__ cw,
    const int* __restrict__ cnt, const int* __restrict__ tok,
    const void* Wd, const void* Wsd, f16* WdT, f16* WsdT, const int* flag)
{
  __shared__ __align__(16) char smbuf[16384];
  const int bid = blockIdx.x;
  const int g = bid/5, r = bid%5;
  if (r == 0){
    f16* As = (f16*)smbuf;                 // 128*32 f16 = 8192 B
    f16* Bg = (f16*)(smbuf + 8192);        // 64*32  f16 = 4096 B
    f16* Bu = (f16*)(smbuf + 12288);       // 64*32  f16 = 4096 B
    gu_body_t(Xh, WsgT, WsuT, WgT, WuT, A1s, P, sgate, cw, cnt, tok, g, As, Bg, Bu);
    return;
  }
  int idx = 4*g + (r-1);
  f16* Tt = (f16*)smbuf;                   // 64*TP f16 = 9216 B
  const void* S; f16* D; int K, N, nx;
  if (idx < 5632){ S = Wd; D = WdT; K = 11264; N = 2048; nx = 32; }
  else { idx -= 5632; S = Wsd; D = WsdT; K = 5632; N = 2048; nx = 32; }
  const int n0 = (idx % nx)*64, k0 = (idx / nx)*64;
  if (*flag) tcvt64<true >(S, D, K, N, 0, n0, k0, Tt);
  else       tcvt64<false>(S, D, K, N, 0, n0, k0, Tt);
}

// ---------------- FULL: down GEMM (R0-proven body) ----------------
// z<8: routed expert z, K=1408, compacted rows (early-exit past cnt[z]).
// z=8,9: shared expert K-chunks of 2816.
__global__ __launch_bounds__(256) void down_gemm_t(
    const f16* __restrict__ Pm, const f16* __restrict__ A1s,
    const f16* __restrict__ WdT, const f16* __restrict__ WsdT,
    const int* __restrict__ cnt,
    float* __restrict__ downR, float* __restrict__ shp)
{
  __shared__ f16 As[128*32];
  __shared__ f16 Bs[128*32];
  const int z = blockIdx.z;
  const int m0 = blockIdx.y*128, n0 = blockIdx.x*128;
  const f16 *A, *B; int lda, ldk, KT; float* C;
  if (z < 8){
    if (m0 >= cnt[z]) return;
    A = Pm + (size_t)z*1024*1408 + (size_t)m0*1408; lda = 1408;
    B = WdT + (size_t)z*1408; ldk = 11264; KT = 44;
    C = downR + (size_t)z*1024*2048;
  } else {
    A = A1s + (size_t)(z-8)*2816 + (size_t)m0*5632; lda = 5632;
    B = WsdT + (size_t)(z-8)*2816; ldk = 5632; KT = 88;
    C = shp + (size_t)(z-8)*2097152;
  }
  const f16* Arow = A;
  const f16* Brow = B + (size_t)n0*ldk;
  const int tid = threadIdx.x, lane = tid&63, wave = tid>>6;
  const int wm = wave>>1, wn = wave&1, lr = lane&15, q = lane>>4;

  const f32x4 z4 = {0.f,0.f,0.f,0.f};
  f32x4 acc[4][4];
#pragma unroll
  for (int mi = 0; mi < 4; ++mi)
#pragma unroll
    for (int ni = 0; ni < 4; ++ni) acc[mi][ni] = z4;

  for (int kt = 0; kt < KT; ++kt){
    __syncthreads();
    stage_T128(Arow, lda, kt*32, As);
    stage_T128(Brow, ldk, kt*32, Bs);
    __syncthreads();
    half8 af[4], bf[4];
#pragma unroll
    for (int mi = 0; mi < 4; ++mi)
      af[mi] = *(const half8*)(As + (wm*64 + mi*16 + lr)*32 + q*8);
#pragma unroll
    for (int ni = 0; ni < 4; ++ni)
      bf[ni] = *(const half8*)(Bs + (wn*64 + ni*16 + lr)*32 + q*8);
#pragma unroll
    for (int ni = 0; ni < 4; ++ni)
#pragma unroll
      for (int mi = 0; mi < 4; ++mi)
        acc[mi][ni] = __builtin_amdgcn_mfma_f32_16x16x32_f16(af[mi], bf[ni], acc[mi][ni], 0, 0, 0);
  }
#pragma unroll
  for (int mi = 0; mi < 4; ++mi)
#pragma unroll
    for (int ni = 0; ni < 4; ++ni)
#pragma unroll
      for (int r = 0; r < 4; ++r){
        const int row = m0 + wm*64 + mi*16 + q*4 + r;
        const int col = n0 + wn*64 + ni*16 + lr;
        C[(size_t)row*2048 + col] = acc[mi][ni][r];
      }
}

// ---------------- FULL: final = 0.5*(sh0+sh1 + gather of token's 4 rows) ----------------
__global__ __launch_bounds__(256) void final_g(
    const float4* __restrict__ sh0, const float4* __restrict__ sh1,
    const float4* __restrict__ downR, const int* __restrict__ inv,
    void* __restrict__ out, const int* __restrict__ flag){
  const int t = blockIdx.x;
  const int4 iv = *(const int4*)(inv + t*4);
  const int idx[4] = {iv.x, iv.y, iv.z, iv.w};
#pragma unroll
  for (int jj = 0; jj < 2; ++jj){
    const int j = threadIdx.x + jj*256;         // float4 index within 512-wide row
    const size_t b = (size_t)t*512 + j;
    const float4 a = sh0[b], c = sh1[b];
    float v0 = a.x + c.x, v1 = a.y + c.y, v2 = a.z + c.z, v3 = a.w + c.w;
#pragma unroll
    for (int k = 0; k < 4; ++k){
      if (idx[k] >= 0){
        const float4 d = downR[(size_t)idx[k]*512 + j];
        v0 += d.x; v1 += d.y; v2 += d.z; v3 += d.w;
      }
    }
    v0 *= 0.5f; v1 *= 0.5f; v2 *= 0.5f; v3 *= 0.5f;
    if (*flag){
      float4 o; o.x=v0; o.y=v1; o.z=v2; o.w=v3;
      ((float4*)out)[b] = o;
    } else {
      uint2 o;
      o.x = (uint32_t)f2b(v0) | ((uint32_t)f2b(v1) << 16);
      o.y = (uint32_t)f2b(v2) | ((uint32_t)f2b(v3) << 16);
      ((uint2*)out)[b] = o;
    }
  }
}

// ================= FALLBACK (round-3) kernels =================
#define LDBT 40
#define ABUF 4096
#define BBUF 2560
struct BR { float v[8]; };
template<bool F32>
__device__ __forceinline__ void loadB(const void* __restrict__ B, size_t ldb, int k0, int n0, BR& r){
  const int t = threadIdx.x, c = t&63, kg = t>>6;
  if (F32){
    const float* p = (const float*)B + (size_t)(k0 + kg*8)*ldb + (n0 + c);
#pragma unroll
    for (int j = 0; j < 8; ++j) r.v[j] = p[(size_t)j*ldb];
  } else {
    const u16* p = (const u16*)B + (size_t)(k0 + kg*8)*ldb + (n0 + c);
#pragma unroll
    for (int j = 0; j < 8; ++j) r.v[j] = b2f(p[(size_t)j*ldb]);
  }
}
__device__ __forceinline__ void storeB(const BR& r, f16* BT){
  const int t = threadIdx.x, c = t&63, kg = t>>6;
  half8 h;
#pragma unroll
  for (int j = 0; j < 8; ++j) h[j] = (f16)r.v[j];
  *(half8*)(BT + c*LDBT + kg*8) = h;
}
template<bool F32>
__device__ void gu_body_r(const f16* __restrict__ Arow, const void* __restrict__ Bgp,
                          const void* __restrict__ Bup, f16* __restrict__ outp,
                          const float* __restrict__ rs, int rs_stride,
                          int ldb, int ldout, int m0, int n0,
                          f16* As, f16* BgT, f16* BuT)
{
  const int tid = threadIdx.x, lane = tid&63, wave = tid>>6;
  const int wm = wave>>1, wn = wave&1, lr = lane&15, q = lane>>4;
  const f32x4 z4 = {0.f,0.f,0.f,0.f};
  f32x4 ag[4][2], au[4][2];
#pragma unroll
  for (int mi = 0; mi < 4; ++mi)
#pragma unroll
    for (int ni = 0; ni < 2; ++ni){ ag[mi][ni] = z4; au[mi][ni] = z4; }
  const int KT = 64;
  BR rg, ru;
  loadB<F32>(Bgp, ldb, 0, n0, rg);
  loadB<F32>(Bup, ldb, 0, n0, ru);
  storeB(rg, BgT); storeB(ru, BuT);
  stage_T128(Arow, 2048, 0, As);
  loadB<F32>(Bgp, ldb, 32, n0, rg);
  loadB<F32>(Bup, ldb, 32, n0, ru);
  __syncthreads();
  for (int kt = 0; kt < KT; ++kt){
    const int cur = kt&1, nxt = cur^1;
    if (kt+1 < KT){
      storeB(rg, BgT + nxt*BBUF);
      storeB(ru, BuT + nxt*BBUF);
      stage_T128(Arow, 2048, (kt+1)*32, As + nxt*ABUF);
    }
    if (kt+2 < KT){
      loadB<F32>(Bgp, ldb, (kt+2)*32, n0, rg);
      loadB<F32>(Bup, ldb, (kt+2)*32, n0, ru);
    }
    const f16* Ac = As + cur*ABUF;
    const f16* Bgc = BgT + cur*BBUF;
    const f16* Buc = BuT + cur*BBUF;
    half8 af[4];
#pragma unroll
    for (int mi = 0; mi < 4; ++mi)
      af[mi] = *(const half8*)(Ac + (wm*64 + mi*16 + lr)*32 + q*8);
#pragma unroll
    for (int ni = 0; ni < 2; ++ni){
      const half8 bfg = *(const half8*)(Bgc + (wn*32 + ni*16 + lr)*LDBT + q*8);
      const half8 bfu = *(const half8*)(Buc + (wn*32 + ni*16 + lr)*LDBT + q*8);
#pragma unroll
      for (int mi = 0; mi < 4; ++mi){
        ag[mi][ni] = __builtin_amdgcn_mfma_f32_16x16x32_f16(af[mi], bfg, ag[mi][ni], 0, 0, 0);
        au[mi][ni] = __builtin_amdgcn_mfma_f32_16x16x32_f16(af[mi], bfu, au[mi][ni], 0, 0, 0);
      }
    }
    __syncthreads();
  }
  float rsv[4][4];
#pragma unroll
  for (int mi = 0; mi < 4; ++mi)
#pragma unroll
    for (int r = 0; r < 4; ++r)
      rsv[mi][r] = rs[(size_t)(m0 + wm*64 + mi*16 + q*4 + r)*rs_stride];
#pragma unroll
  for (int mi = 0; mi < 4; ++mi)
#pragma unroll
    for (int ni = 0; ni < 2; ++ni)
#pragma unroll
      for (int r = 0; r < 4; ++r){
        const int row = m0 + wm*64 + mi*16 + q*4 + r;
        const int col = n0 + wn*32 + ni*16 + lr;
        const float g = ag[mi][ni][r];
        const float v = (g / (1.f + __expf(-g))) * au[mi][ni][r] * rsv[mi][r];
        outp[(size_t)row*ldout + col] = (f16)v;
      }
}
__global__ __launch_bounds__(256) void gu_gemm_r(
    const f16* __restrict__ Xh, const void* Wsg, const void* Wsu,
    const void* Wg, const void* Wu, f16* __restrict__ A1s, f16* __restrict__ P,
    const float* __restrict__ sgate, const float* __restrict__ combine, const int* flag)
{
  __shared__ f16 As[2*ABUF];
  __shared__ f16 BgT[2*BBUF];
  __shared__ f16 BuT[2*BBUF];
  const bool f32v = (*flag != 0);
  int bid = blockIdx.x;
  const void *Bg, *Bu; f16* outp; const float* rs;
  int rs_stride, ldb, ldout, m0, n0;
  if (bid < 704){
    n0 = (bid % 88)*64; m0 = (bid / 88)*128;
    Bg = Wsg; Bu = Wsu; outp = A1s; rs = sgate;
    rs_stride = 1; ldb = 5632; ldout = 5632;
  } else {
    bid -= 704;
    const int e = bid / 176, r = bid % 176;
    n0 = (r % 22)*64; m0 = (r / 22)*128;
    const size_t off = (size_t)e*2048*1408;
    Bg = f32v ? (const void*)((const float*)Wg + off) : (const void*)((const u16*)Wg + off);
    Bu = f32v ? (const void*)((const float*)Wu + off) : (const void*)((const u16*)Wu + off);
    outp = P + (size_t)e*1408; rs = combine + e;
    rs_stride = 8; ldb = 1408; ldout = 11264;
  }
  const f16* Arow = Xh + (size_t)m0*2048;
  if (f32v) gu_body_r<true >(Arow, Bg, Bu, outp, rs, rs_stride, ldb, ldout, m0, n0, As, BgT, BuT);
  else      gu_body_r<false>(Arow, Bg, Bu, outp, rs, rs_stride, ldb, ldout, m0, n0, As, BgT, BuT);
}
template<bool F32>
__device__ void down_body_r(const f16* __restrict__ Arow, int lda, const void* __restrict__ B,
                            float* __restrict__ C, int m0, int n0, f16* As, f16* BT)
{
  const int tid = threadIdx.x, lane = tid&63, wave = tid>>6;
  const int wm = wave>>1, wn = wave&1, lr = lane&15, q = lane>>4;
  const f32x4 z4 = {0.f,0.f,0.f,0.f};
  f32x4 acc[4][2];
#pragma unroll
  for (int mi = 0; mi < 4; ++mi)
#pragma unroll
    for (int ni = 0; ni < 2; ++ni) acc[mi][ni] = z4;
  const int KT = 176;
  BR rb;
  loadB<F32>(B, 2048, 0, n0, rb);
  storeB(rb, BT);
  stage_T128(Arow, lda, 0, As);
  loadB<F32>(B, 2048, 32, n0, rb);
  __syncthreads();
  for (int kt = 0; kt < KT; ++kt){
    const int cur = kt&1, nxt = cur^1;
    if (kt+1 < KT){
      storeB(rb, BT + nxt*BBUF);
      stage_T128(Arow, lda, (kt+1)*32, As + nxt*ABUF);
    }
    if (kt+2 < KT) loadB<F32>(B, 2048, (kt+2)*32, n0, rb);
    const f16* Ac = As + cur*ABUF;
    const f16* Bc = BT + cur*BBUF;
    half8 af[4];
#pragma unroll
    for (int mi = 0; mi < 4; ++mi)
      af[mi] = *(const half8*)(Ac + (wm*64 + mi*16 + lr)*32 + q*8);
#pragma unroll
    for (int ni = 0; ni < 2; ++ni){
      const half8 bf = *(const half8*)(Bc + (wn*32 + ni*16 + lr)*LDBT + q*8);
#pragma unroll
      for (int mi = 0; mi < 4; ++mi)
        acc[mi][ni] = __builtin_amdgcn_mfma_f32_16x16x32_f16(af[mi], bf, acc[mi][ni], 0, 0, 0);
    }
    __syncthreads();
  }
#pragma unroll
  for (int mi = 0; mi < 4; ++mi)
#pragma unroll
    for (int ni = 0; ni < 2; ++ni)
#pragma unroll
      for (int r = 0; r < 4; ++r){
        const int row = m0 + wm*64 + mi*16 + q*4 + r;
        const int col = n0 + wn*32 + ni*16 + lr;
        C[(size_t)row*2048 + col] = acc[mi][ni][r];
      }
}
__global__ __launch_bounds__(256) void down_gemm_r(
    const f16* __restrict__ Pm, const f16* __restrict__ A1s,
    const void* Wd, const void* Wsd,
    float* __restrict__ c0, float* __restrict__ c1, float* __restrict__ c2, const int* flag)
{
  __shared__ f16 As[2*ABUF];
  __shared__ f16 BT[2*BBUF];
  const int z = blockIdx.z;
  const bool f32v = (*flag != 0);
  const f16* A; const void* B; float* C; int lda;
  if (z == 0){ A = Pm; B = Wd; C = c0; lda = 11264; }
  else if (z == 1){
    A = Pm + 5632;
    B = f32v ? (const void*)((const float*)Wd + (size_t)5632*2048)
             : (const void*)((const u16*)Wd + (size_t)5632*2048);
    C = c1; lda = 11264;
  } else { A = A1s; B = Wsd; C = c2; lda = 5632; }
  const int m0 = blockIdx.y*128, n0 = blockIdx.x*64;
  const f16* Arow = A + (size_t)m0*lda;
  if (f32v) down_body_r<true >(Arow, lda, B, C, m0, n0, As, BT);
  else      down_body_r<false>(Arow, lda, B, C, m0, n0, As, BT);
}
__global__ __launch_bounds__(256) void final3(
    const float4* __restrict__ b0, const float4* __restrict__ b1, const float4* __restrict__ b2,
    void* __restrict__ out, const int* flag, int n4){
  const int i = blockIdx.x*256 + threadIdx.x;
  if (i >= n4) return;
  const float4 a = b0[i], b = b1[i], c = b2[i];
  const float v0 = 0.5f*(a.x + b.x + c.x);
  const float v1 = 0.5f*(a.y + b.y + c.y);
  const float v2 = 0.5f*(a.z + b.z + c.z);
  const float v3 = 0.5f*(a.w + b.w + c.w);
  if (*flag){
    float4 o; o.x=v0; o.y=v1; o.z=v2; o.w=v3;
    ((float4*)out)[i] = o;
  } else {
    uint2 o;
    o.x = (uint32_t)f2b(v0) | ((uint32_t)f2b(v1) << 16);
    o.y = (uint32_t)f2b(v2) | ((uint32_t)f2b(v3) << 16);
    ((uint2*)out)[i] = o;
  }
}

// ================= host =================
extern "C" void kernel_launch(void* const* d_in, const int* in_sizes, int n_in,
                              void* d_out, int out_size, void* d_ws, size_t ws_size,
                              hipStream_t stream)
{
  (void)in_sizes; (void)n_in; (void)out_size;
  const void* x   = d_in[0];
  const void* Wg  = d_in[1];
  const void* Wu  = d_in[2];
  const void* Wd  = d_in[3];
  const void* Wsg = d_in[4];
  const void* Wsu = d_in[5];
  const void* Wsd = d_in[6];
  const void* Wr  = d_in[7];
  const void* Wxg = d_in[8];

  char* ws = (char*)d_ws;
  size_t off = 0;
  auto alloc = [&](size_t bytes)->char*{
    char* p = ws + off; off = (off + bytes + 255) & ~(size_t)255; return p;
  };
  float* combine = (float*)alloc(32768);
  float* sgate   = (float*)alloc(4096);
  int*   flag    = (int*)  alloc(4096);
  int*   cnt     = (int*)  alloc(4096);
  int*   tok     = (int*)  alloc(8*1024*4);
  float* cw      = (float*)alloc(8*1024*4);
  int*   inv     = (int*)  alloc(1024*4*4);
  f16*   Xh      = (f16*)  alloc((size_t)1024*2048*2);
  f16*   A1s     = (f16*)  alloc((size_t)1024*5632*2);
  f16*   P       = (f16*)  alloc((size_t)8*1024*1408*2);        // per-expert compacted
  float* shp     = (float*)alloc((size_t)3*2097152*4);          // 2 shared partials (+1 fallback)
  float* downR   = (float*)alloc((size_t)8*1024*2048*4);        // routed down, compacted fp32
  f16*   WsgT    = (f16*)  alloc((size_t)5632*2048*2);
  f16*   WsuT    = (f16*)  alloc((size_t)5632*2048*2);
  f16*   WgT     = (f16*)  alloc((size_t)8*1408*2048*2);
  f16*   WuT     = (f16*)  alloc((size_t)8*1408*2048*2);
  f16*   WdT     = (f16*)  alloc((size_t)2048*11264*2);
  f16*   WsdT    = (f16*)  alloc((size_t)2048*5632*2);
  const size_t NEED_FULL = off;

  if (ws_size >= NEED_FULL){
    router_conv2<<<dim3(1024), dim3(256), 0, stream>>>(x, Wr, Wxg, Xh, combine, sgate, flag);
    prep_gu<<<dim3(16897), dim3(256), 0, stream>>>(
        Wsg, Wsu, Wg, Wu, WsgT, WsuT, WgT, WuT,
        combine, cnt, tok, cw, inv, flag);
    gu_fused<<<dim3(10560), dim3(256), 0, stream>>>(
        Xh, WsgT, WsuT, WgT, WuT, A1s, P, sgate, cw, cnt, tok,
        Wd, Wsd, WdT, WsdT, flag);
    down_gemm_t<<<dim3(16, 8, 10), dim3(256), 0, stream>>>(P, A1s, WdT, WsdT, cnt, downR, shp);
    final_g<<<dim3(1024), dim3(256), 0, stream>>>(
        (const float4*)shp, (const float4*)(shp + 2097152), (const float4*)downR,
        inv, d_out, flag);
  } else {
    // fallback: round-3 register-staging path (needs only ~65 MB: up through shp)
    detect_kernel<<<dim3(1), dim3(64), 0, stream>>>((const uint32_t*)x, flag);
    router_conv<<<dim3(1024), dim3(256), 0, stream>>>(x, Wr, Wxg, Xh, combine, sgate, flag);
    float* b0 = shp;
    float* b1 = shp + 2097152;
    float* b2 = shp + 2*2097152;
    gu_gemm_r<<<dim3(2112), dim3(256), 0, stream>>>(
        Xh, Wsg, Wsu, Wg, Wu, A1s, P, sgate, combine, flag);
    down_gemm_r<<<dim3(32, 8, 3), dim3(256), 0, stream>>>(P, A1s, Wd, Wsd, b0, b1, b2, flag);
    final3<<<dim3(2048), dim3(256), 0, stream>>>(
        (const float4*)b0, (const float4*)b1, (const float4*)b2, d_out, flag, 524288);
  }
}